// Round 4
// baseline (343.642 us; speedup 1.0000x reference)
//
#include <hip/hip_runtime.h>
#include <hip/hip_bf16.h>

typedef __hip_bfloat16 bf16;

#define NGRAPH 128

// ---------------- degree histogram ----------------
__global__ __launch_bounds__(256) void deg_kernel(const int* __restrict__ ei,
                                                  int* __restrict__ deg, int E, int N) {
    int e = blockIdx.x * 256 + threadIdx.x;
    if (e < E) {
        int d = ei[E + e];                 // dst = ei[1][e]
        d = max(0, min(d, N - 1));
        atomicAdd(&deg[d], 1);
    }
}

// ---------------- scan: per-block sums ----------------
__global__ __launch_bounds__(256) void scan1_kernel(const int* __restrict__ deg,
                                                    int* __restrict__ bsum, int N) {
    __shared__ int tmp[256];
    int i = blockIdx.x * 256 + threadIdx.x;
    tmp[threadIdx.x] = (i < N) ? deg[i] : 0;
    __syncthreads();
    for (int off = 128; off > 0; off >>= 1) {
        if (threadIdx.x < off) tmp[threadIdx.x] += tmp[threadIdx.x + off];
        __syncthreads();
    }
    if (threadIdx.x == 0) bsum[blockIdx.x] = tmp[0];
}

// ---------------- scan: exclusive scan of block sums ----------------
__global__ __launch_bounds__(256) void scan2_kernel(const int* __restrict__ bsum,
                                                    int* __restrict__ boff, int nb) {
    __shared__ int tmp[256];
    __shared__ int carry;
    int tid = threadIdx.x;
    if (tid == 0) carry = 0;
    __syncthreads();
    for (int base = 0; base < nb; base += 256) {
        int i = base + tid;
        int v = (i < nb) ? bsum[i] : 0;
        tmp[tid] = v;
        __syncthreads();
        for (int off = 1; off < 256; off <<= 1) {
            int t = (tid >= off) ? tmp[tid - off] : 0;
            __syncthreads();
            tmp[tid] += t;
            __syncthreads();
        }
        if (i < nb) boff[i] = carry + tmp[tid] - v;
        __syncthreads();
        if (tid == 0) carry += tmp[255];
        __syncthreads();
    }
}

// ---------------- scan: per-element row_start + dinv ----------------
__global__ __launch_bounds__(256) void scan3_kernel(const int* __restrict__ deg,
                                                    const int* __restrict__ boff,
                                                    int* __restrict__ row_start,
                                                    float* __restrict__ dinv, int N) {
    __shared__ int tmp[256];
    int i = blockIdx.x * 256 + threadIdx.x;
    int v = (i < N) ? deg[i] : 0;
    tmp[threadIdx.x] = v;
    __syncthreads();
    for (int off = 1; off < 256; off <<= 1) {
        int t = (threadIdx.x >= off) ? tmp[threadIdx.x - off] : 0;
        __syncthreads();
        tmp[threadIdx.x] += t;
        __syncthreads();
    }
    if (i < N) {
        int excl = tmp[threadIdx.x] - v;
        int rs = boff[blockIdx.x] + excl;
        row_start[i] = rs;
        if (i == N - 1) row_start[N] = rs + v;
        dinv[i] = rsqrtf((float)(v + 1));   // +1 self loop
    }
}

// ---------------- CSR fill (dst-sorted src list) ----------------
__global__ __launch_bounds__(256) void fill_kernel(const int* __restrict__ ei,
                                                   const int* __restrict__ row_start,
                                                   int* __restrict__ cursor,
                                                   int* __restrict__ csr_src, int E, int N) {
    int e = blockIdx.x * 256 + threadIdx.x;
    if (e < E) {
        int s = ei[e];     s = max(0, min(s, N - 1));
        int d = ei[E + e]; d = max(0, min(d, N - 1));
        int pos = row_start[d] + atomicAdd(&cursor[d], 1);
        if (pos >= 0 && pos < E) csr_src[pos] = s;
    }
}

// ---------------- P1 = (x @ W1) * dinv  (wave-per-node-pair, grid-stride) ----------------
__global__ __launch_bounds__(256) void proj_kernel(const float* __restrict__ A,
                                                   const float* __restrict__ W,
                                                   const float* __restrict__ dinv,
                                                   bf16* __restrict__ P, int N) {
    __shared__ float Wl[4096];
    for (int i = threadIdx.x; i < 4096; i += 256) Wl[i] = W[i];
    __syncthreads();
    int lane = threadIdx.x & 63;
    int wid = (blockIdx.x * 256 + threadIdx.x) >> 6;
    int nwaves = (gridDim.x * 256) >> 6;
    int npairs = (N + 1) >> 1;
    for (int p = wid; p < npairs; p += nwaves) {
        int n0 = p * 2, n1 = n0 + 1;
        float a0 = A[(size_t)n0 * 64 + lane];
        float a1 = (n1 < N) ? A[(size_t)n1 * 64 + lane] : 0.f;
        float s0 = 0.f, s1 = 0.f;
#pragma unroll
        for (int k = 0; k < 64; ++k) {
            float w = Wl[k * 64 + lane];          // one LDS read feeds both nodes
            s0 += __shfl(a0, k) * w;
            s1 += __shfl(a1, k) * w;
        }
        P[(size_t)n0 * 64 + lane] = __float2bfloat16(s0 * dinv[n0]);
        if (n1 < N) P[(size_t)n1 * 64 + lane] = __float2bfloat16(s1 * dinv[n1]);
    }
}

// ---- unpack uint4 (8 bf16) and accumulate with weight w ----
__device__ __forceinline__ void acc_bf8(float* acc, uint4 v, float w) {
    unsigned int u[4] = {v.x, v.y, v.z, v.w};
#pragma unroll
    for (int m = 0; m < 4; ++m) {
        float lo = __uint_as_float(u[m] << 16);
        float hi = __uint_as_float(u[m] & 0xffff0000u);
        acc[2 * m]     += w * lo;
        acc[2 * m + 1] += w * hi;
    }
}

// ---- paired wide gather: two nodes, 4 independent row-streams + 2 self rows
//      in flight (R0 load pattern, doubled). Direct global csr_src reads
//      (R0-proven codegen: exec-masked conditional loads, row 0 for masked).
//      On return, EVERY lane holds in accA/accB the neighbor-sum (incl. self)
//      for features c*8 .. c*8+7 (c = lane&7). ----
__device__ __forceinline__ void gather_pair(float accA[8], float accB[8],
                                            const bf16* __restrict__ P,
                                            const int* __restrict__ csr_src,
                                            int begA, int endA, int begB, int endB,
                                            int nodeA, int nodeB,
                                            int r, int c, int N) {
#pragma unroll
    for (int k = 0; k < 8; ++k) { accA[k] = 0.f; accB[k] = 0.f; }
    // self-loop rows: independent, issue first
    uint4 vsA = *(const uint4*)(P + (size_t)nodeA * 64 + c * 8);   // nodeA < N always
    uint4 vsB = make_uint4(0u, 0u, 0u, 0u);
    if (nodeB < N) vsB = *(const uint4*)(P + (size_t)nodeB * 64 + c * 8);
    int tA = endA - begA, tB = endB - begB;
    int tmax = tA > tB ? tA : tB;
    for (int i = 0; i < tmax; i += 16) {
        int pA0 = begA + i + r, pA1 = pA0 + 8;
        int pB0 = begB + i + r, pB1 = pB0 + 8;
        int okA0 = pA0 < endA, okA1 = pA1 < endA;
        int okB0 = pB0 < endB, okB1 = pB1 < endB;
        int sA0 = okA0 ? csr_src[pA0] : 0;
        int sA1 = okA1 ? csr_src[pA1] : 0;
        int sB0 = okB0 ? csr_src[pB0] : 0;
        int sB1 = okB1 ? csr_src[pB1] : 0;
        uint4 vA0 = *(const uint4*)(P + (size_t)sA0 * 64 + c * 8);
        uint4 vA1 = *(const uint4*)(P + (size_t)sA1 * 64 + c * 8);
        uint4 vB0 = *(const uint4*)(P + (size_t)sB0 * 64 + c * 8);
        uint4 vB1 = *(const uint4*)(P + (size_t)sB1 * 64 + c * 8);
        acc_bf8(accA, vA0, okA0 ? 1.f : 0.f);
        acc_bf8(accA, vA1, okA1 ? 1.f : 0.f);
        acc_bf8(accB, vB0, okB0 ? 1.f : 0.f);
        acc_bf8(accB, vB1, okB1 ? 1.f : 0.f);
    }
    // butterfly-reduce across the 8 r-groups (lane bits 3..5)
#pragma unroll
    for (int mask = 8; mask <= 32; mask <<= 1) {
#pragma unroll
        for (int k = 0; k < 8; ++k) {
            accA[k] += __shfl_xor(accA[k], mask);
            accB[k] += __shfl_xor(accB[k], mask);
        }
    }
    // self-loop chunk (added once per lane, after reduction — same order as R0)
    acc_bf8(accA, vsA, 1.f);
    acc_bf8(accB, vsB, 1.f);
}

// ---- layer1 aggregate + fused layer2 projection (pair-per-iteration, grid-stride) ----
__global__ __launch_bounds__(256, 2) void agg_proj_kernel(const bf16* __restrict__ P1,
                                                          const int* __restrict__ row_start,
                                                          const int* __restrict__ csr_src,
                                                          const float* __restrict__ dinv,
                                                          const float* __restrict__ b1,
                                                          const float* __restrict__ W2,
                                                          bf16* __restrict__ P2, int N) {
    __shared__ float Wl[4096];
    for (int i = threadIdx.x; i < 4096; i += 256) Wl[i] = W2[i];
    __syncthreads();
    int lane = threadIdx.x & 63;
    int r = lane >> 3, c = lane & 7;
    float bb[8];
#pragma unroll
    for (int k = 0; k < 8; ++k) bb[k] = b1[c * 8 + k];
    int wid = (blockIdx.x * 256 + threadIdx.x) >> 6;
    int nwaves = (gridDim.x * 256) >> 6;
    int npairs = (N + 1) >> 1;
    for (int p = wid; p < npairs; p += nwaves) {
        int n0 = p * 2, n1 = n0 + 1;
        int rsA = row_start[n0];
        int rsM = row_start[n0 + 1];
        int rsB = row_start[(n1 + 1) <= N ? (n1 + 1) : N];
        int endB = (n1 < N) ? rsB : rsM;
        float accA[8], accB[8];
        gather_pair(accA, accB, P1, csr_src, rsA, rsM, rsM, endB, n0, n1, r, c, N);
        float dvA = dinv[n0];
        float dvB = (n1 < N) ? dinv[n1] : 1.f;
        float hA[8], hB[8];
#pragma unroll
        for (int k = 0; k < 8; ++k) {
            hA[k] = fmaxf(accA[k] * dvA + bb[k], 0.f);
            hB[k] = fmaxf(accB[k] * dvB + bb[k], 0.f);
        }
        // fused projection, one Wl read feeds both nodes
        float a2A = 0.f, a2B = 0.f;
#pragma unroll
        for (int c2 = 0; c2 < 8; ++c2) {
#pragma unroll
            for (int jj = 0; jj < 8; ++jj) {
                float w = Wl[(c2 * 8 + jj) * 64 + lane];
                a2A += __shfl(hA[jj], c2) * w;
                a2B += __shfl(hB[jj], c2) * w;
            }
        }
        P2[(size_t)n0 * 64 + lane] = __float2bfloat16(a2A * dvA);
        if (n1 < N) P2[(size_t)n1 * 64 + lane] = __float2bfloat16(a2B * dvB);
    }
}

// ---- layer2 aggregate + fused mean-pool accumulation (pair-per-iteration) ----
__global__ __launch_bounds__(256, 2) void agg_pool_kernel(const bf16* __restrict__ P2,
                                                          const int* __restrict__ row_start,
                                                          const int* __restrict__ csr_src,
                                                          const float* __restrict__ dinv,
                                                          const float* __restrict__ b2,
                                                          const int* __restrict__ batch,
                                                          float* __restrict__ out_h,
                                                          float* __restrict__ accum, int N) {
    int lane = threadIdx.x & 63;
    int r = lane >> 3, c = lane & 7;
    float bb[8];
#pragma unroll
    for (int k = 0; k < 8; ++k) bb[k] = b2[c * 8 + k];
    // transpose source lane: lane l pulls feature l from lane src
    int src = ((lane & 7) << 3) | (lane >> 3);
    int wid = (blockIdx.x * 256 + threadIdx.x) >> 6;
    int nwaves = (gridDim.x * 256) >> 6;
    int npairs = (N + 1) >> 1;
    for (int p = wid; p < npairs; p += nwaves) {
        int n0 = p * 2, n1 = n0 + 1;
        int rsA = row_start[n0];
        int rsM = row_start[n0 + 1];
        int rsB = row_start[(n1 + 1) <= N ? (n1 + 1) : N];
        int endB = (n1 < N) ? rsB : rsM;
        float accA[8], accB[8];
        gather_pair(accA, accB, P2, csr_src, rsA, rsM, rsM, endB, n0, n1, r, c, N);
        float dvA = dinv[n0];
        float dvB = (n1 < N) ? dinv[n1] : 1.f;
        float hA[8], hB[8];
#pragma unroll
        for (int k = 0; k < 8; ++k) {
            hA[k] = accA[k] * dvA + bb[k];
            hB[k] = accB[k] * dvB + bb[k];
        }
        // in-register transpose: lane l ends up holding feature l
        float valA = 0.f, valB = 0.f;
#pragma unroll
        for (int k = 0; k < 8; ++k) {
            float tA = __shfl(hA[k], src);
            float tB = __shfl(hB[k], src);
            valA = ((lane & 7) == k) ? tA : valA;
            valB = ((lane & 7) == k) ? tB : valB;
        }
        out_h[(size_t)n0 * 64 + lane] = valA;
        int gA = max(0, min(batch[n0], NGRAPH - 1));
        if (n1 < N) {
            out_h[(size_t)n1 * 64 + lane] = valB;
            int gB = max(0, min(batch[n1], NGRAPH - 1));
            if (gA == gB) {
                atomicAdd(&accum[gA * 64 + lane], valA + valB);   // one atomic per pair
            } else {
                atomicAdd(&accum[gA * 64 + lane], valA);
                atomicAdd(&accum[gB * 64 + lane], valB);
            }
        } else {
            atomicAdd(&accum[gA * 64 + lane], valA);
        }
    }
}

// ---------------- finalize pool (divide by count) + classifier head ----------------
__device__ __forceinline__ int lower_bound_dev(const int* a, int n, int key) {
    int lo = 0, hi = n;
    while (lo < hi) {
        int mid = (lo + hi) >> 1;
        if (a[mid] < key) lo = mid + 1; else hi = mid;
    }
    return lo;
}

__global__ __launch_bounds__(64) void final_kernel(const float* __restrict__ accum,
                                                   const int* __restrict__ batch,
                                                   const float* __restrict__ Wc1,
                                                   const float* __restrict__ bc1,
                                                   const float* __restrict__ Wc2,
                                                   const float* __restrict__ bc2,
                                                   float* __restrict__ out_reps,
                                                   float* __restrict__ out_logits, int N) {
    __shared__ float rep[64];
    __shared__ float t[64];
    int g = blockIdx.x;
    int f = threadIdx.x;
    int lo = lower_bound_dev(batch, N, g);
    int hi = lower_bound_dev(batch, N, g + 1);
    float cnt = (float)(hi - lo);
    float r = accum[g * 64 + f] / fmaxf(cnt, 1.f);
    out_reps[g * 64 + f] = r;
    rep[f] = r;
    __syncthreads();
    float acc = bc1[f];
#pragma unroll
    for (int k = 0; k < 64; ++k) acc += rep[k] * Wc1[k * 64 + f];
    t[f] = fmaxf(acc, 0.f);
    __syncthreads();
    if (f < 16) {
        float a2 = bc2[f];
#pragma unroll
        for (int k = 0; k < 64; ++k) a2 += t[k] * Wc2[k * 16 + f];
        out_logits[g * 16 + f] = a2;
    }
}

extern "C" void kernel_launch(void* const* d_in, const int* in_sizes, int n_in,
                              void* d_out, int out_size, void* d_ws, size_t ws_size,
                              hipStream_t stream) {
    const float* x    = (const float*)d_in[0];
    const int*   ei   = (const int*)d_in[1];
    const int*   batch= (const int*)d_in[2];
    const float* W1   = (const float*)d_in[3];
    const float* b1   = (const float*)d_in[4];
    const float* W2   = (const float*)d_in[5];
    const float* b2   = (const float*)d_in[6];
    const float* Wc1  = (const float*)d_in[7];
    const float* bc1  = (const float*)d_in[8];
    const float* Wc2  = (const float*)d_in[9];
    const float* bc2  = (const float*)d_in[10];

    const int N = in_sizes[2];          // 50000
    const int E = in_sizes[1] / 2;      // 800000

    // ---- workspace layout (~7.3 MB) ----
    char* ws = (char*)d_ws;
    size_t off = 0;
    auto alloc = [&](size_t bytes) { void* p = ws + off; off += (bytes + 255) & ~(size_t)255; return p; };
    int*   deg       = (int*)  alloc((size_t)N * 4);
    int*   cursor    = (int*)  alloc((size_t)N * 4);
    float* accum     = (float*)alloc((size_t)NGRAPH * 64 * 4);
    size_t zero_bytes = off;                       // deg + cursor + accum start at 0
    float* dinv      = (float*)alloc((size_t)N * 4);
    int*   row_start = (int*)  alloc((size_t)(N + 1) * 4);
    int*   bsum      = (int*)  alloc(1024);
    int*   boff      = (int*)  alloc(1024);
    int*   csr_src   = (int*)  alloc((size_t)E * 4);
    bf16*  P1        = (bf16*) alloc((size_t)N * 64 * 2);
    bf16*  P2        = (bf16*) alloc((size_t)N * 64 * 2);
    (void)ws_size; (void)n_in; (void)out_size;

    float* out_h      = (float*)d_out;                      // [N,64]
    float* out_reps   = out_h + (size_t)N * 64;             // [128,64]
    float* out_logits = out_reps + (size_t)NGRAPH * 64;     // [128,16]

    int nbE = (E + 255) / 256;
    int nbN = (N + 255) / 256;
    const int GS = 2048;                 // grid-stride blocks (8192 waves)

    hipMemsetAsync(d_ws, 0, zero_bytes, stream);
    deg_kernel<<<nbE, 256, 0, stream>>>(ei, deg, E, N);
    scan1_kernel<<<nbN, 256, 0, stream>>>(deg, bsum, N);
    scan2_kernel<<<1, 256, 0, stream>>>(bsum, boff, nbN);
    scan3_kernel<<<nbN, 256, 0, stream>>>(deg, boff, row_start, dinv, N);
    fill_kernel<<<nbE, 256, 0, stream>>>(ei, row_start, cursor, csr_src, E, N);

    proj_kernel<<<GS, 256, 0, stream>>>(x, W1, dinv, P1, N);
    agg_proj_kernel<<<GS, 256, 0, stream>>>(P1, row_start, csr_src, dinv, b1, W2, P2, N);
    agg_pool_kernel<<<GS, 256, 0, stream>>>(P2, row_start, csr_src, dinv, b2, batch,
                                            out_h, accum, N);
    final_kernel<<<NGRAPH, 64, 0, stream>>>(accum, batch, Wc1, bc1, Wc2, bc2,
                                            out_reps, out_logits, N);
}

// Round 5
// 332.404 us; speedup vs baseline: 1.0338x; 1.0338x over previous
//
#include <hip/hip_runtime.h>
#include <hip/hip_bf16.h>

typedef __hip_bfloat16 bf16;

#define NGRAPH 128
#define CHUNK 8        // contiguous nodes per wave in agg kernels
#define IREG_CAP 256   // edge indices held in registers per wave (4 x 64 lanes)

// ---------------- degree histogram ----------------
__global__ __launch_bounds__(256) void deg_kernel(const int* __restrict__ ei,
                                                  int* __restrict__ deg, int E, int N) {
    int e = blockIdx.x * 256 + threadIdx.x;
    if (e < E) {
        int d = ei[E + e];                 // dst = ei[1][e]
        d = max(0, min(d, N - 1));
        atomicAdd(&deg[d], 1);
    }
}

// ---------------- scan: per-block sums ----------------
__global__ __launch_bounds__(256) void scan1_kernel(const int* __restrict__ deg,
                                                    int* __restrict__ bsum, int N) {
    __shared__ int tmp[256];
    int i = blockIdx.x * 256 + threadIdx.x;
    tmp[threadIdx.x] = (i < N) ? deg[i] : 0;
    __syncthreads();
    for (int off = 128; off > 0; off >>= 1) {
        if (threadIdx.x < off) tmp[threadIdx.x] += tmp[threadIdx.x + off];
        __syncthreads();
    }
    if (threadIdx.x == 0) bsum[blockIdx.x] = tmp[0];
}

// ---------------- scan: exclusive scan of block sums ----------------
__global__ __launch_bounds__(256) void scan2_kernel(const int* __restrict__ bsum,
                                                    int* __restrict__ boff, int nb) {
    __shared__ int tmp[256];
    __shared__ int carry;
    int tid = threadIdx.x;
    if (tid == 0) carry = 0;
    __syncthreads();
    for (int base = 0; base < nb; base += 256) {
        int i = base + tid;
        int v = (i < nb) ? bsum[i] : 0;
        tmp[tid] = v;
        __syncthreads();
        for (int off = 1; off < 256; off <<= 1) {
            int t = (tid >= off) ? tmp[tid - off] : 0;
            __syncthreads();
            tmp[tid] += t;
            __syncthreads();
        }
        if (i < nb) boff[i] = carry + tmp[tid] - v;
        __syncthreads();
        if (tid == 0) carry += tmp[255];
        __syncthreads();
    }
}

// ---------------- scan: per-element row_start + dinv ----------------
__global__ __launch_bounds__(256) void scan3_kernel(const int* __restrict__ deg,
                                                    const int* __restrict__ boff,
                                                    int* __restrict__ row_start,
                                                    float* __restrict__ dinv, int N) {
    __shared__ int tmp[256];
    int i = blockIdx.x * 256 + threadIdx.x;
    int v = (i < N) ? deg[i] : 0;
    tmp[threadIdx.x] = v;
    __syncthreads();
    for (int off = 1; off < 256; off <<= 1) {
        int t = (threadIdx.x >= off) ? tmp[threadIdx.x - off] : 0;
        __syncthreads();
        tmp[threadIdx.x] += t;
        __syncthreads();
    }
    if (i < N) {
        int excl = tmp[threadIdx.x] - v;
        int rs = boff[blockIdx.x] + excl;
        row_start[i] = rs;
        if (i == N - 1) row_start[N] = rs + v;
        dinv[i] = rsqrtf((float)(v + 1));   // +1 self loop
    }
}

// ---------------- CSR fill (dst-sorted src list) ----------------
__global__ __launch_bounds__(256) void fill_kernel(const int* __restrict__ ei,
                                                   const int* __restrict__ row_start,
                                                   int* __restrict__ cursor,
                                                   int* __restrict__ csr_src, int E, int N) {
    int e = blockIdx.x * 256 + threadIdx.x;
    if (e < E) {
        int s = ei[e];     s = max(0, min(s, N - 1));
        int d = ei[E + e]; d = max(0, min(d, N - 1));
        int pos = row_start[d] + atomicAdd(&cursor[d], 1);
        if (pos >= 0 && pos < E) csr_src[pos] = s;
    }
}

// ---------------- P1 = (x @ W1) * dinv  (wave-per-node-pair, grid-stride) ----------------
__global__ __launch_bounds__(256) void proj_kernel(const float* __restrict__ A,
                                                   const float* __restrict__ W,
                                                   const float* __restrict__ dinv,
                                                   bf16* __restrict__ P, int N) {
    __shared__ float Wl[4096];
    for (int i = threadIdx.x; i < 4096; i += 256) Wl[i] = W[i];
    __syncthreads();
    int lane = threadIdx.x & 63;
    int wid = (blockIdx.x * 256 + threadIdx.x) >> 6;
    int nwaves = (gridDim.x * 256) >> 6;
    int npairs = (N + 1) >> 1;
    for (int p = wid; p < npairs; p += nwaves) {
        int n0 = p * 2, n1 = n0 + 1;
        float a0 = A[(size_t)n0 * 64 + lane];
        float a1 = (n1 < N) ? A[(size_t)n1 * 64 + lane] : 0.f;
        float s0 = 0.f, s1 = 0.f;
#pragma unroll
        for (int k = 0; k < 64; ++k) {
            float w = Wl[k * 64 + lane];          // one LDS read feeds both nodes
            s0 += __shfl(a0, k) * w;
            s1 += __shfl(a1, k) * w;
        }
        P[(size_t)n0 * 64 + lane] = __float2bfloat16(s0 * dinv[n0]);
        if (n1 < N) P[(size_t)n1 * 64 + lane] = __float2bfloat16(s1 * dinv[n1]);
    }
}

// ---- unpack uint4 (8 bf16) and accumulate with weight w ----
__device__ __forceinline__ void acc_bf8(float* acc, uint4 v, float w) {
    unsigned int u[4] = {v.x, v.y, v.z, v.w};
#pragma unroll
    for (int m = 0; m < 4; ++m) {
        float lo = __uint_as_float(u[m] << 16);
        float hi = __uint_as_float(u[m] & 0xffff0000u);
        acc[2 * m]     += w * lo;
        acc[2 * m + 1] += w * hi;
    }
}

// ---- fetch a chunk-local edge index from the 4-register idx cache via shfl.
//      u must be a valid chunk-local position (< nE); value only used when ok. ----
__device__ __forceinline__ int idx_from_regs(int ir0, int ir1, int ir2, int ir3,
                                             const int* __restrict__ csr_src,
                                             int e0, int u) {
    int lsel = u & 63;
    int t = u >> 6;
    int v0 = __shfl(ir0, lsel);
    int v1 = __shfl(ir1, lsel);
    int v2 = __shfl(ir2, lsel);
    int v3 = __shfl(ir3, lsel);
    int s = (t == 0) ? v0 : (t == 1) ? v1 : (t == 2) ? v2 : v3;
    if (u >= IREG_CAP) s = csr_src[e0 + u];   // rare overflow (avg chunk = 128 edges)
    return s;
}

// ---- single-node wide gather, R0 load pattern (2 uint4 streams in flight),
//      indices from the per-wave register cache (no idx memory wait per node).
//      On return, EVERY lane holds in acc[0..7] the neighbor-sum for features
//      c*8 .. c*8+7 (c = lane&7). beg/end are chunk-local. ----
__device__ __forceinline__ void gather_reg(float acc[8],
                                           const bf16* __restrict__ P,
                                           int ir0, int ir1, int ir2, int ir3,
                                           const int* __restrict__ csr_src, int e0,
                                           int beg, int end, int r, int c) {
#pragma unroll
    for (int k = 0; k < 8; ++k) acc[k] = 0.f;
    for (int i = beg; i < end; i += 16) {
        int q0 = i + r, q1 = i + 8 + r;
        int ok0 = q0 < end, ok1 = q1 < end;
        int u0 = ok0 ? q0 : beg;              // any valid position for masked lanes
        int u1 = ok1 ? q1 : beg;
        int s0 = idx_from_regs(ir0, ir1, ir2, ir3, csr_src, e0, u0);
        int s1 = idx_from_regs(ir0, ir1, ir2, ir3, csr_src, e0, u1);
        uint4 v0 = *(const uint4*)(P + (size_t)s0 * 64 + c * 8);
        uint4 v1 = *(const uint4*)(P + (size_t)s1 * 64 + c * 8);
        acc_bf8(acc, v0, ok0 ? 1.f : 0.f);
        acc_bf8(acc, v1, ok1 ? 1.f : 0.f);
    }
    // butterfly-reduce across the 8 r-groups (lane bits 3..5)
#pragma unroll
    for (int mask = 8; mask <= 32; mask <<= 1) {
#pragma unroll
        for (int k = 0; k < 8; ++k) acc[k] += __shfl_xor(acc[k], mask);
    }
}

// ---- layer1 aggregate + fused layer2 projection (chunk-per-wave, reg-idx) ----
__global__ __launch_bounds__(256) void agg_proj_kernel(const bf16* __restrict__ P1,
                                                       const int* __restrict__ row_start,
                                                       const int* __restrict__ csr_src,
                                                       const float* __restrict__ dinv,
                                                       const float* __restrict__ b1,
                                                       const float* __restrict__ W2,
                                                       bf16* __restrict__ P2, int N, int E) {
    __shared__ float Wl[4096];
    for (int i = threadIdx.x; i < 4096; i += 256) Wl[i] = W2[i];
    __syncthreads();
    int lane = threadIdx.x & 63;
    int wid = (blockIdx.x * 256 + threadIdx.x) >> 6;
    int base = wid * CHUNK;
    if (base >= N) return;
    int r = lane >> 3, c = lane & 7;

    // chunk row bounds + dinv: one lane-parallel coalesced load each
    int rsv = 0;
    if (lane <= CHUNK) { int idx = base + lane; rsv = row_start[idx > N ? N : idx]; }
    float dvv = 0.f;
    if (lane < CHUNK) { int idx = base + lane; dvv = dinv[idx < N ? idx : N - 1]; }
    int e0 = __shfl(rsv, 0);
    int nE = __shfl(rsv, CHUNK) - e0;

    // preload the chunk's edge indices into 4 registers (coalesced, one wait/chunk)
    int ir0 = (lane           < nE) ? csr_src[e0 + lane]       : 0;
    int ir1 = (lane + 64      < nE) ? csr_src[e0 + lane + 64]  : 0;
    int ir2 = (lane + 128     < nE) ? csr_src[e0 + lane + 128] : 0;
    int ir3 = (lane + 192     < nE) ? csr_src[e0 + lane + 192] : 0;

    float bb[8];
#pragma unroll
    for (int k = 0; k < 8; ++k) bb[k] = b1[c * 8 + k];

#pragma unroll 1
    for (int j = 0; j < CHUNK; ++j) {
        int node = base + j;
        if (node >= N) break;
        int beg = __shfl(rsv, j)     - e0;
        int end = __shfl(rsv, j + 1) - e0;
        float acc[8];
        gather_reg(acc, P1, ir0, ir1, ir2, ir3, csr_src, e0, beg, end, r, c);
        // self-loop chunk (added once per lane, after reduction)
        uint4 vs = *(const uint4*)(P1 + (size_t)node * 64 + c * 8);
        acc_bf8(acc, vs, 1.f);
        float dv = __shfl(dvv, j);
        float h[8];
#pragma unroll
        for (int k = 0; k < 8; ++k) h[k] = fmaxf(acc[k] * dv + bb[k], 0.f);
        // fused projection: P2[node][lane] = (h1 @ W2)[lane] * dinv
        float a2 = 0.f;
#pragma unroll
        for (int c2 = 0; c2 < 8; ++c2) {
#pragma unroll
            for (int jj = 0; jj < 8; ++jj) {
                a2 += __shfl(h[jj], c2) * Wl[(c2 * 8 + jj) * 64 + lane];
            }
        }
        P2[(size_t)node * 64 + lane] = __float2bfloat16(a2 * dv);
    }
    (void)E;
}

// ---- layer2 aggregate + fused mean-pool accumulation (chunk-per-wave, reg-idx) ----
__global__ __launch_bounds__(256) void agg_pool_kernel(const bf16* __restrict__ P2,
                                                       const int* __restrict__ row_start,
                                                       const int* __restrict__ csr_src,
                                                       const float* __restrict__ dinv,
                                                       const float* __restrict__ b2,
                                                       const int* __restrict__ batch,
                                                       float* __restrict__ out_h,
                                                       float* __restrict__ accum, int N, int E) {
    int lane = threadIdx.x & 63;
    int wid = (blockIdx.x * 256 + threadIdx.x) >> 6;
    int base = wid * CHUNK;
    if (base >= N) return;
    int r = lane >> 3, c = lane & 7;

    int rsv = 0;
    if (lane <= CHUNK) { int idx = base + lane; rsv = row_start[idx > N ? N : idx]; }
    float dvv = 0.f; int bvv = 0;
    if (lane < CHUNK) {
        int idx = base + lane; int ii = idx < N ? idx : N - 1;
        dvv = dinv[ii]; bvv = batch[ii];
    }
    int e0 = __shfl(rsv, 0);
    int nE = __shfl(rsv, CHUNK) - e0;

    int ir0 = (lane           < nE) ? csr_src[e0 + lane]       : 0;
    int ir1 = (lane + 64      < nE) ? csr_src[e0 + lane + 64]  : 0;
    int ir2 = (lane + 128     < nE) ? csr_src[e0 + lane + 128] : 0;
    int ir3 = (lane + 192     < nE) ? csr_src[e0 + lane + 192] : 0;

    float bb[8];
#pragma unroll
    for (int k = 0; k < 8; ++k) bb[k] = b2[c * 8 + k];
    // transpose source lane: lane l pulls feature l from lane src
    int src = ((lane & 7) << 3) | (lane >> 3);

    float poolv = 0.f;
    int curg = max(0, min(__shfl(bvv, 0), NGRAPH - 1));

#pragma unroll 1
    for (int j = 0; j < CHUNK; ++j) {
        int node = base + j;
        if (node >= N) break;
        int beg = __shfl(rsv, j)     - e0;
        int end = __shfl(rsv, j + 1) - e0;
        float acc[8];
        gather_reg(acc, P2, ir0, ir1, ir2, ir3, csr_src, e0, beg, end, r, c);
        uint4 vs = *(const uint4*)(P2 + (size_t)node * 64 + c * 8);
        acc_bf8(acc, vs, 1.f);
        float dv = __shfl(dvv, j);
        float h[8];
#pragma unroll
        for (int k = 0; k < 8; ++k) h[k] = acc[k] * dv + bb[k];
        // in-register transpose: lane l ends up holding feature l
        float val = 0.f;
#pragma unroll
        for (int k = 0; k < 8; ++k) {
            float t = __shfl(h[k], src);
            val = ((lane & 7) == k) ? t : val;
        }
        out_h[(size_t)node * 64 + lane] = val;
        // run-batched pool: one atomic per graph-run within the chunk
        int g = max(0, min(__shfl(bvv, j), NGRAPH - 1));
        if (g != curg) { atomicAdd(&accum[curg * 64 + lane], poolv); poolv = 0.f; curg = g; }
        poolv += val;
    }
    atomicAdd(&accum[curg * 64 + lane], poolv);   // flush chunk remainder
    (void)E;
}

// ---------------- finalize pool (divide by count) + classifier head ----------------
__device__ __forceinline__ int lower_bound_dev(const int* a, int n, int key) {
    int lo = 0, hi = n;
    while (lo < hi) {
        int mid = (lo + hi) >> 1;
        if (a[mid] < key) lo = mid + 1; else hi = mid;
    }
    return lo;
}

__global__ __launch_bounds__(64) void final_kernel(const float* __restrict__ accum,
                                                   const int* __restrict__ batch,
                                                   const float* __restrict__ Wc1,
                                                   const float* __restrict__ bc1,
                                                   const float* __restrict__ Wc2,
                                                   const float* __restrict__ bc2,
                                                   float* __restrict__ out_reps,
                                                   float* __restrict__ out_logits, int N) {
    __shared__ float rep[64];
    __shared__ float t[64];
    int g = blockIdx.x;
    int f = threadIdx.x;
    int lo = lower_bound_dev(batch, N, g);
    int hi = lower_bound_dev(batch, N, g + 1);
    float cnt = (float)(hi - lo);
    float r = accum[g * 64 + f] / fmaxf(cnt, 1.f);
    out_reps[g * 64 + f] = r;
    rep[f] = r;
    __syncthreads();
    float acc = bc1[f];
#pragma unroll
    for (int k = 0; k < 64; ++k) acc += rep[k] * Wc1[k * 64 + f];
    t[f] = fmaxf(acc, 0.f);
    __syncthreads();
    if (f < 16) {
        float a2 = bc2[f];
#pragma unroll
        for (int k = 0; k < 64; ++k) a2 += t[k] * Wc2[k * 16 + f];
        out_logits[g * 16 + f] = a2;
    }
}

extern "C" void kernel_launch(void* const* d_in, const int* in_sizes, int n_in,
                              void* d_out, int out_size, void* d_ws, size_t ws_size,
                              hipStream_t stream) {
    const float* x    = (const float*)d_in[0];
    const int*   ei   = (const int*)d_in[1];
    const int*   batch= (const int*)d_in[2];
    const float* W1   = (const float*)d_in[3];
    const float* b1   = (const float*)d_in[4];
    const float* W2   = (const float*)d_in[5];
    const float* b2   = (const float*)d_in[6];
    const float* Wc1  = (const float*)d_in[7];
    const float* bc1  = (const float*)d_in[8];
    const float* Wc2  = (const float*)d_in[9];
    const float* bc2  = (const float*)d_in[10];

    const int N = in_sizes[2];          // 50000
    const int E = in_sizes[1] / 2;      // 800000

    // ---- workspace layout (~7.3 MB) ----
    char* ws = (char*)d_ws;
    size_t off = 0;
    auto alloc = [&](size_t bytes) { void* p = ws + off; off += (bytes + 255) & ~(size_t)255; return p; };
    int*   deg       = (int*)  alloc((size_t)N * 4);
    int*   cursor    = (int*)  alloc((size_t)N * 4);
    float* accum     = (float*)alloc((size_t)NGRAPH * 64 * 4);
    size_t zero_bytes = off;                       // deg + cursor + accum start at 0
    float* dinv      = (float*)alloc((size_t)N * 4);
    int*   row_start = (int*)  alloc((size_t)(N + 1) * 4);
    int*   bsum      = (int*)  alloc(1024);
    int*   boff      = (int*)  alloc(1024);
    int*   csr_src   = (int*)  alloc((size_t)E * 4);
    bf16*  P1        = (bf16*) alloc((size_t)N * 64 * 2);
    bf16*  P2        = (bf16*) alloc((size_t)N * 64 * 2);
    (void)ws_size; (void)n_in; (void)out_size;

    float* out_h      = (float*)d_out;                      // [N,64]
    float* out_reps   = out_h + (size_t)N * 64;             // [128,64]
    float* out_logits = out_reps + (size_t)NGRAPH * 64;     // [128,16]

    int nbE = (E + 255) / 256;
    int nbN = (N + 255) / 256;
    const int GS = 2048;                 // grid-stride blocks for proj

    // chunked agg kernels: one wave per CHUNK contiguous nodes (exact grid)
    int nwaves_c = (N + CHUNK - 1) / CHUNK;
    int nblk_c   = (nwaves_c + 3) / 4;

    hipMemsetAsync(d_ws, 0, zero_bytes, stream);
    deg_kernel<<<nbE, 256, 0, stream>>>(ei, deg, E, N);
    scan1_kernel<<<nbN, 256, 0, stream>>>(deg, bsum, N);
    scan2_kernel<<<1, 256, 0, stream>>>(bsum, boff, nbN);
    scan3_kernel<<<nbN, 256, 0, stream>>>(deg, boff, row_start, dinv, N);
    fill_kernel<<<nbE, 256, 0, stream>>>(ei, row_start, cursor, csr_src, E, N);

    proj_kernel<<<GS, 256, 0, stream>>>(x, W1, dinv, P1, N);
    agg_proj_kernel<<<nblk_c, 256, 0, stream>>>(P1, row_start, csr_src, dinv, b1, W2, P2, N, E);
    agg_pool_kernel<<<nblk_c, 256, 0, stream>>>(P2, row_start, csr_src, dinv, b2, batch,
                                                out_h, accum, N, E);
    final_kernel<<<NGRAPH, 64, 0, stream>>>(accum, batch, Wc1, bc1, Wc2, bc2,
                                            out_reps, out_logits, N);
}

// Round 6
// 300.252 us; speedup vs baseline: 1.1445x; 1.1071x over previous
//
#include <hip/hip_runtime.h>
#include <hip/hip_bf16.h>

typedef __hip_bfloat16 bf16;

#define NGRAPH 128

// ---------------- degree histogram ----------------
__global__ __launch_bounds__(256) void deg_kernel(const int* __restrict__ ei,
                                                  int* __restrict__ deg, int E, int N) {
    int e = blockIdx.x * 256 + threadIdx.x;
    if (e < E) {
        int d = ei[E + e];                 // dst = ei[1][e]
        d = max(0, min(d, N - 1));
        atomicAdd(&deg[d], 1);
    }
}

// ---------------- scan: per-block sums ----------------
__global__ __launch_bounds__(256) void scan1_kernel(const int* __restrict__ deg,
                                                    int* __restrict__ bsum, int N) {
    __shared__ int tmp[256];
    int i = blockIdx.x * 256 + threadIdx.x;
    tmp[threadIdx.x] = (i < N) ? deg[i] : 0;
    __syncthreads();
    for (int off = 128; off > 0; off >>= 1) {
        if (threadIdx.x < off) tmp[threadIdx.x] += tmp[threadIdx.x + off];
        __syncthreads();
    }
    if (threadIdx.x == 0) bsum[blockIdx.x] = tmp[0];
}

// ---------------- scan: exclusive scan of block sums ----------------
__global__ __launch_bounds__(256) void scan2_kernel(const int* __restrict__ bsum,
                                                    int* __restrict__ boff, int nb) {
    __shared__ int tmp[256];
    __shared__ int carry;
    int tid = threadIdx.x;
    if (tid == 0) carry = 0;
    __syncthreads();
    for (int base = 0; base < nb; base += 256) {
        int i = base + tid;
        int v = (i < nb) ? bsum[i] : 0;
        tmp[tid] = v;
        __syncthreads();
        for (int off = 1; off < 256; off <<= 1) {
            int t = (tid >= off) ? tmp[tid - off] : 0;
            __syncthreads();
            tmp[tid] += t;
            __syncthreads();
        }
        if (i < nb) boff[i] = carry + tmp[tid] - v;
        __syncthreads();
        if (tid == 0) carry += tmp[255];
        __syncthreads();
    }
}

// ---------------- scan: per-element row_start + dinv ----------------
__global__ __launch_bounds__(256) void scan3_kernel(const int* __restrict__ deg,
                                                    const int* __restrict__ boff,
                                                    int* __restrict__ row_start,
                                                    float* __restrict__ dinv, int N) {
    __shared__ int tmp[256];
    int i = blockIdx.x * 256 + threadIdx.x;
    int v = (i < N) ? deg[i] : 0;
    tmp[threadIdx.x] = v;
    __syncthreads();
    for (int off = 1; off < 256; off <<= 1) {
        int t = (threadIdx.x >= off) ? tmp[threadIdx.x - off] : 0;
        __syncthreads();
        tmp[threadIdx.x] += t;
        __syncthreads();
    }
    if (i < N) {
        int excl = tmp[threadIdx.x] - v;
        int rs = boff[blockIdx.x] + excl;
        row_start[i] = rs;
        if (i == N - 1) row_start[N] = rs + v;
        dinv[i] = rsqrtf((float)(v + 1));   // +1 self loop
    }
}

// ---------------- fused: CSR fill (blocks [0,nbE)) + P1 projection (rest) ----------------
// fill needs row_start; proj needs only dinv — both ready after scan3, so they
// run CONCURRENTLY in one launch on disjoint block ranges.
__global__ __launch_bounds__(256) void fillproj_kernel(const int* __restrict__ ei,
                                                       const int* __restrict__ row_start,
                                                       int* __restrict__ cursor,
                                                       int* __restrict__ csr_src,
                                                       const float* __restrict__ A,
                                                       const float* __restrict__ W,
                                                       const float* __restrict__ dinv,
                                                       bf16* __restrict__ P,
                                                       int E, int N, int nbE) {
    __shared__ float Wl[4096];
    if ((int)blockIdx.x < nbE) {
        // ---- CSR fill part (dst-sorted src list) ----
        int e = blockIdx.x * 256 + threadIdx.x;
        if (e < E) {
            int s = ei[e];     s = max(0, min(s, N - 1));
            int d = ei[E + e]; d = max(0, min(d, N - 1));
            int pos = row_start[d] + atomicAdd(&cursor[d], 1);
            if (pos >= 0 && pos < E) csr_src[pos] = s;
        }
        return;
    }
    // ---- P1 = (x @ W1) * dinv  (wave-per-node-pair, grid-stride) ----
    for (int i = threadIdx.x; i < 4096; i += 256) Wl[i] = W[i];
    __syncthreads();
    int lane = threadIdx.x & 63;
    int wid = (((int)blockIdx.x - nbE) * 256 + threadIdx.x) >> 6;
    int nwaves = (((int)gridDim.x - nbE) * 256) >> 6;
    int npairs = (N + 1) >> 1;
    for (int p = wid; p < npairs; p += nwaves) {
        int n0 = p * 2, n1 = n0 + 1;
        float a0 = A[(size_t)n0 * 64 + lane];
        float a1 = (n1 < N) ? A[(size_t)n1 * 64 + lane] : 0.f;
        float s0 = 0.f, s1 = 0.f;
#pragma unroll
        for (int k = 0; k < 64; ++k) {
            float w = Wl[k * 64 + lane];          // one LDS read feeds both nodes
            s0 += __shfl(a0, k) * w;
            s1 += __shfl(a1, k) * w;
        }
        P[(size_t)n0 * 64 + lane] = __float2bfloat16(s0 * dinv[n0]);
        if (n1 < N) P[(size_t)n1 * 64 + lane] = __float2bfloat16(s1 * dinv[n1]);
    }
}

// ---- unpack uint4 (8 bf16) and accumulate with weight w ----
__device__ __forceinline__ void acc_bf8(float* acc, uint4 v, float w) {
    unsigned int u[4] = {v.x, v.y, v.z, v.w};
#pragma unroll
    for (int m = 0; m < 4; ++m) {
        float lo = __uint_as_float(u[m] << 16);
        float hi = __uint_as_float(u[m] & 0xffff0000u);
        acc[2 * m]     += w * lo;
        acc[2 * m + 1] += w * hi;
    }
}

// ---- wide gather: 8 rows per load instruction, unroll x2 (16 rows in flight).
//      EXACT R0 body (proven 64-VGPR dual-stream codegen).
//      On return, EVERY lane holds in acc[0..7] the neighbor-sum for features
//      c*8 .. c*8+7 (c = lane&7), identical across the 8 r-groups. ----
__device__ __forceinline__ void gather_sum8(float* acc,
                                            const bf16* __restrict__ P,
                                            const int* __restrict__ csr_src,
                                            int beg, int end, int r, int c) {
#pragma unroll
    for (int k = 0; k < 8; ++k) acc[k] = 0.f;
    for (int i = beg; i < end; i += 16) {
        int r0 = i + r, r1 = i + 8 + r;
        int ok0 = (r0 < end), ok1 = (r1 < end);
        int s0 = ok0 ? csr_src[r0] : 0;
        int s1 = ok1 ? csr_src[r1] : 0;
        float w0 = ok0 ? 1.f : 0.f;
        float w1 = ok1 ? 1.f : 0.f;
        uint4 v0 = *(const uint4*)(P + (size_t)s0 * 64 + c * 8);
        uint4 v1 = *(const uint4*)(P + (size_t)s1 * 64 + c * 8);
        acc_bf8(acc, v0, w0);
        acc_bf8(acc, v1, w1);
    }
    // butterfly-reduce across the 8 r-groups (lane bits 3..5)
#pragma unroll
    for (int mask = 8; mask <= 32; mask <<= 1) {
#pragma unroll
        for (int k = 0; k < 8; ++k) acc[k] += __shfl_xor(acc[k], mask);
    }
}

// ---- layer1 aggregate + fused layer2 projection (R0 body, contiguous node range) ----
__global__ __launch_bounds__(256) void agg_proj_kernel(const bf16* __restrict__ P1,
                                                       const int* __restrict__ row_start,
                                                       const int* __restrict__ csr_src,
                                                       const float* __restrict__ dinv,
                                                       const float* __restrict__ b1,
                                                       const float* __restrict__ W2,
                                                       bf16* __restrict__ P2, int N) {
    __shared__ float Wl[4096];
    for (int i = threadIdx.x; i < 4096; i += 256) Wl[i] = W2[i];
    __syncthreads();
    int lane = threadIdx.x & 63;
    int r = lane >> 3, c = lane & 7;
    float bb[8];
#pragma unroll
    for (int k = 0; k < 8; ++k) bb[k] = b1[c * 8 + k];
    int wid = (blockIdx.x * 256 + threadIdx.x) >> 6;
    int nwaves = (gridDim.x * 256) >> 6;
    int cpn = (N + nwaves - 1) / nwaves;         // contiguous nodes per wave
    int node0 = wid * cpn;
    int node1 = node0 + cpn; if (node1 > N) node1 = N;
    for (int node = node0; node < node1; ++node) {
        float acc[8];
        gather_sum8(acc, P1, csr_src, row_start[node], row_start[node + 1], r, c);
        // self-loop chunk (added once per lane, after reduction)
        uint4 vs = *(const uint4*)(P1 + (size_t)node * 64 + c * 8);
        acc_bf8(acc, vs, 1.f);
        float dv = dinv[node];
        float h[8];
#pragma unroll
        for (int k = 0; k < 8; ++k) h[k] = fmaxf(acc[k] * dv + bb[k], 0.f);
        // fused projection: P2[node][lane] = (h1 @ W2)[lane] * dinv
        float acc2 = 0.f;
#pragma unroll
        for (int c2 = 0; c2 < 8; ++c2) {
#pragma unroll
            for (int j = 0; j < 8; ++j) {
                acc2 += __shfl(h[j], c2) * Wl[(c2 * 8 + j) * 64 + lane];
            }
        }
        P2[(size_t)node * 64 + lane] = __float2bfloat16(acc2 * dv);
    }
}

// ---- layer2 aggregate + fused mean-pool accumulation (R0 body, contiguous range) ----
__global__ __launch_bounds__(256) void agg_pool_kernel(const bf16* __restrict__ P2,
                                                       const int* __restrict__ row_start,
                                                       const int* __restrict__ csr_src,
                                                       const float* __restrict__ dinv,
                                                       const float* __restrict__ b2,
                                                       const int* __restrict__ batch,
                                                       float* __restrict__ out_h,
                                                       float* __restrict__ accum, int N) {
    int lane = threadIdx.x & 63;
    int r = lane >> 3, c = lane & 7;
    float bb[8];
#pragma unroll
    for (int k = 0; k < 8; ++k) bb[k] = b2[c * 8 + k];
    // transpose source lane: holds c' = lane>>3, i.e. features (lane>>3)*8+k
    int src = ((lane & 7) << 3) | (lane >> 3);
    int wid = (blockIdx.x * 256 + threadIdx.x) >> 6;
    int nwaves = (gridDim.x * 256) >> 6;
    int cpn = (N + nwaves - 1) / nwaves;
    int node0 = wid * cpn;
    int node1 = node0 + cpn; if (node1 > N) node1 = N;
    for (int node = node0; node < node1; ++node) {
        float acc[8];
        gather_sum8(acc, P2, csr_src, row_start[node], row_start[node + 1], r, c);
        uint4 vs = *(const uint4*)(P2 + (size_t)node * 64 + c * 8);
        acc_bf8(acc, vs, 1.f);
        float dv = dinv[node];
        float h[8];
#pragma unroll
        for (int k = 0; k < 8; ++k) h[k] = acc[k] * dv + bb[k];
        // in-register transpose: lane l ends up holding feature l
        float val = 0.f;
#pragma unroll
        for (int k = 0; k < 8; ++k) {
            float t = __shfl(h[k], src);
            val = ((lane & 7) == k) ? t : val;
        }
        // coalesced wave-wide store (256 B contiguous) + ONE wave-wide atomic
        out_h[(size_t)node * 64 + lane] = val;
        int g = batch[node];
        g = max(0, min(g, NGRAPH - 1));
        atomicAdd(&accum[g * 64 + lane], val);
    }
}

// ---------------- finalize pool (divide by count) + classifier head ----------------
__device__ __forceinline__ int lower_bound_dev(const int* a, int n, int key) {
    int lo = 0, hi = n;
    while (lo < hi) {
        int mid = (lo + hi) >> 1;
        if (a[mid] < key) lo = mid + 1; else hi = mid;
    }
    return lo;
}

__global__ __launch_bounds__(64) void final_kernel(const float* __restrict__ accum,
                                                   const int* __restrict__ batch,
                                                   const float* __restrict__ Wc1,
                                                   const float* __restrict__ bc1,
                                                   const float* __restrict__ Wc2,
                                                   const float* __restrict__ bc2,
                                                   float* __restrict__ out_reps,
                                                   float* __restrict__ out_logits, int N) {
    __shared__ float rep[64];
    __shared__ float t[64];
    int g = blockIdx.x;
    int f = threadIdx.x;
    int lo = lower_bound_dev(batch, N, g);
    int hi = lower_bound_dev(batch, N, g + 1);
    float cnt = (float)(hi - lo);
    float r = accum[g * 64 + f] / fmaxf(cnt, 1.f);
    out_reps[g * 64 + f] = r;
    rep[f] = r;
    __syncthreads();
    float acc = bc1[f];
#pragma unroll
    for (int k = 0; k < 64; ++k) acc += rep[k] * Wc1[k * 64 + f];
    t[f] = fmaxf(acc, 0.f);
    __syncthreads();
    if (f < 16) {
        float a2 = bc2[f];
#pragma unroll
        for (int k = 0; k < 64; ++k) a2 += t[k] * Wc2[k * 16 + f];
        out_logits[g * 16 + f] = a2;
    }
}

extern "C" void kernel_launch(void* const* d_in, const int* in_sizes, int n_in,
                              void* d_out, int out_size, void* d_ws, size_t ws_size,
                              hipStream_t stream) {
    const float* x    = (const float*)d_in[0];
    const int*   ei   = (const int*)d_in[1];
    const int*   batch= (const int*)d_in[2];
    const float* W1   = (const float*)d_in[3];
    const float* b1   = (const float*)d_in[4];
    const float* W2   = (const float*)d_in[5];
    const float* b2   = (const float*)d_in[6];
    const float* Wc1  = (const float*)d_in[7];
    const float* bc1  = (const float*)d_in[8];
    const float* Wc2  = (const float*)d_in[9];
    const float* bc2  = (const float*)d_in[10];

    const int N = in_sizes[2];          // 50000
    const int E = in_sizes[1] / 2;      // 800000

    // ---- workspace layout (~7.3 MB) ----
    char* ws = (char*)d_ws;
    size_t off = 0;
    auto alloc = [&](size_t bytes) { void* p = ws + off; off += (bytes + 255) & ~(size_t)255; return p; };
    int*   deg       = (int*)  alloc((size_t)N * 4);
    int*   cursor    = (int*)  alloc((size_t)N * 4);
    float* accum     = (float*)alloc((size_t)NGRAPH * 64 * 4);
    size_t zero_bytes = off;                       // deg + cursor + accum start at 0
    float* dinv      = (float*)alloc((size_t)N * 4);
    int*   row_start = (int*)  alloc((size_t)(N + 1) * 4);
    int*   bsum      = (int*)  alloc(1024);
    int*   boff      = (int*)  alloc(1024);
    int*   csr_src   = (int*)  alloc((size_t)E * 4);
    bf16*  P1        = (bf16*) alloc((size_t)N * 64 * 2);
    bf16*  P2        = (bf16*) alloc((size_t)N * 64 * 2);
    (void)ws_size; (void)n_in; (void)out_size;

    float* out_h      = (float*)d_out;                      // [N,64]
    float* out_reps   = out_h + (size_t)N * 64;             // [128,64]
    float* out_logits = out_reps + (size_t)NGRAPH * 64;     // [128,16]

    int nbE = (E + 255) / 256;
    int nbN = (N + 255) / 256;
    const int GS = 2048;                 // grid-stride blocks (8192 waves)

    hipMemsetAsync(d_ws, 0, zero_bytes, stream);
    deg_kernel<<<nbE, 256, 0, stream>>>(ei, deg, E, N);
    scan1_kernel<<<nbN, 256, 0, stream>>>(deg, bsum, N);
    scan2_kernel<<<1, 256, 0, stream>>>(bsum, boff, nbN);
    scan3_kernel<<<nbN, 256, 0, stream>>>(deg, boff, row_start, dinv, N);

    // fill and proj are independent after scan3 — run them concurrently
    fillproj_kernel<<<nbE + GS, 256, 0, stream>>>(ei, row_start, cursor, csr_src,
                                                  x, W1, dinv, P1, E, N, nbE);

    agg_proj_kernel<<<GS, 256, 0, stream>>>(P1, row_start, csr_src, dinv, b1, W2, P2, N);
    agg_pool_kernel<<<GS, 256, 0, stream>>>(P2, row_start, csr_src, dinv, b2, batch,
                                            out_h, accum, N);
    final_kernel<<<NGRAPH, 64, 0, stream>>>(accum, batch, Wc1, bc1, Wc2, bc2,
                                            out_reps, out_logits, N);
}

// Round 7
// 297.033 us; speedup vs baseline: 1.1569x; 1.0108x over previous
//
#include <hip/hip_runtime.h>
#include <hip/hip_bf16.h>

typedef __hip_bfloat16 bf16;

#define NGRAPH 128

// ---------------- degree histogram ----------------
__global__ __launch_bounds__(256) void deg_kernel(const int* __restrict__ ei,
                                                  int* __restrict__ deg, int E, int N) {
    int e = blockIdx.x * 256 + threadIdx.x;
    if (e < E) {
        int d = ei[E + e];                 // dst = ei[1][e]
        d = max(0, min(d, N - 1));
        atomicAdd(&deg[d], 1);
    }
}

// ---------------- scan: per-block sums ----------------
__global__ __launch_bounds__(256) void scan1_kernel(const int* __restrict__ deg,
                                                    int* __restrict__ bsum, int N) {
    __shared__ int tmp[256];
    int i = blockIdx.x * 256 + threadIdx.x;
    tmp[threadIdx.x] = (i < N) ? deg[i] : 0;
    __syncthreads();
    for (int off = 128; off > 0; off >>= 1) {
        if (threadIdx.x < off) tmp[threadIdx.x] += tmp[threadIdx.x + off];
        __syncthreads();
    }
    if (threadIdx.x == 0) bsum[blockIdx.x] = tmp[0];
}

// ---------------- scan: exclusive scan of block sums ----------------
__global__ __launch_bounds__(256) void scan2_kernel(const int* __restrict__ bsum,
                                                    int* __restrict__ boff, int nb) {
    __shared__ int tmp[256];
    __shared__ int carry;
    int tid = threadIdx.x;
    if (tid == 0) carry = 0;
    __syncthreads();
    for (int base = 0; base < nb; base += 256) {
        int i = base + tid;
        int v = (i < nb) ? bsum[i] : 0;
        tmp[tid] = v;
        __syncthreads();
        for (int off = 1; off < 256; off <<= 1) {
            int t = (tid >= off) ? tmp[tid - off] : 0;
            __syncthreads();
            tmp[tid] += t;
            __syncthreads();
        }
        if (i < nb) boff[i] = carry + tmp[tid] - v;
        __syncthreads();
        if (tid == 0) carry += tmp[255];
        __syncthreads();
    }
}

// ---------------- scan: per-element row_start + dinv ----------------
__global__ __launch_bounds__(256) void scan3_kernel(const int* __restrict__ deg,
                                                    const int* __restrict__ boff,
                                                    int* __restrict__ row_start,
                                                    float* __restrict__ dinv, int N) {
    __shared__ int tmp[256];
    int i = blockIdx.x * 256 + threadIdx.x;
    int v = (i < N) ? deg[i] : 0;
    tmp[threadIdx.x] = v;
    __syncthreads();
    for (int off = 1; off < 256; off <<= 1) {
        int t = (threadIdx.x >= off) ? tmp[threadIdx.x - off] : 0;
        __syncthreads();
        tmp[threadIdx.x] += t;
        __syncthreads();
    }
    if (i < N) {
        int excl = tmp[threadIdx.x] - v;
        int rs = boff[blockIdx.x] + excl;
        row_start[i] = rs;
        if (i == N - 1) row_start[N] = rs + v;
        dinv[i] = rsqrtf((float)(v + 1));   // +1 self loop
    }
}

// ---------------- fused: CSR fill (blocks [0,nbE)) + P1 projection (rest) ----------------
// fill needs row_start; proj needs only dinv — both ready after scan3, so they
// run CONCURRENTLY in one launch on disjoint block ranges.
// proj branch is the R0 single-node body: minimal live state keeps the FUSED
// kernel in the <=64-VGPR occupancy bucket (R6's paired body hit 104 VGPR and
// halved residency for both branches).
__global__ __launch_bounds__(256) void fillproj_kernel(const int* __restrict__ ei,
                                                       const int* __restrict__ row_start,
                                                       int* __restrict__ cursor,
                                                       int* __restrict__ csr_src,
                                                       const float* __restrict__ A,
                                                       const float* __restrict__ W,
                                                       const float* __restrict__ dinv,
                                                       bf16* __restrict__ P,
                                                       int E, int N, int nbE) {
    __shared__ float Wl[4096];
    if ((int)blockIdx.x < nbE) {
        // ---- CSR fill part (dst-sorted src list) ----
        int e = blockIdx.x * 256 + threadIdx.x;
        if (e < E) {
            int s = ei[e];     s = max(0, min(s, N - 1));
            int d = ei[E + e]; d = max(0, min(d, N - 1));
            int pos = row_start[d] + atomicAdd(&cursor[d], 1);
            if (pos >= 0 && pos < E) csr_src[pos] = s;
        }
        return;
    }
    // ---- P1 = (x @ W1) * dinv  (wave-per-node, grid-stride; R0 body) ----
    for (int i = threadIdx.x; i < 4096; i += 256) Wl[i] = W[i];
    __syncthreads();
    int lane = threadIdx.x & 63;
    int wid = (((int)blockIdx.x - nbE) * 256 + threadIdx.x) >> 6;
    int nwaves = (((int)gridDim.x - nbE) * 256) >> 6;
    for (int node = wid; node < N; node += nwaves) {
        float a = A[(size_t)node * 64 + lane];
        float acc = 0.f;
#pragma unroll
        for (int k = 0; k < 64; ++k) acc += __shfl(a, k) * Wl[k * 64 + lane];
        P[(size_t)node * 64 + lane] = __float2bfloat16(acc * dinv[node]);
    }
}

// ---- unpack uint4 (8 bf16) and accumulate with weight w ----
__device__ __forceinline__ void acc_bf8(float* acc, uint4 v, float w) {
    unsigned int u[4] = {v.x, v.y, v.z, v.w};
#pragma unroll
    for (int m = 0; m < 4; ++m) {
        float lo = __uint_as_float(u[m] << 16);
        float hi = __uint_as_float(u[m] & 0xffff0000u);
        acc[2 * m]     += w * lo;
        acc[2 * m + 1] += w * hi;
    }
}

// ---- wide gather: 8 rows per load instruction, unroll x2 (16 rows in flight).
//      EXACT R0 body (proven 64-VGPR dual-stream codegen).
//      On return, EVERY lane holds in acc[0..7] the neighbor-sum for features
//      c*8 .. c*8+7 (c = lane&7), identical across the 8 r-groups. ----
__device__ __forceinline__ void gather_sum8(float* acc,
                                            const bf16* __restrict__ P,
                                            const int* __restrict__ csr_src,
                                            int beg, int end, int r, int c) {
#pragma unroll
    for (int k = 0; k < 8; ++k) acc[k] = 0.f;
    for (int i = beg; i < end; i += 16) {
        int r0 = i + r, r1 = i + 8 + r;
        int ok0 = (r0 < end), ok1 = (r1 < end);
        int s0 = ok0 ? csr_src[r0] : 0;
        int s1 = ok1 ? csr_src[r1] : 0;
        float w0 = ok0 ? 1.f : 0.f;
        float w1 = ok1 ? 1.f : 0.f;
        uint4 v0 = *(const uint4*)(P + (size_t)s0 * 64 + c * 8);
        uint4 v1 = *(const uint4*)(P + (size_t)s1 * 64 + c * 8);
        acc_bf8(acc, v0, w0);
        acc_bf8(acc, v1, w1);
    }
    // butterfly-reduce across the 8 r-groups (lane bits 3..5)
#pragma unroll
    for (int mask = 8; mask <= 32; mask <<= 1) {
#pragma unroll
        for (int k = 0; k < 8; ++k) acc[k] += __shfl_xor(acc[k], mask);
    }
}

// ---- layer1 aggregate + fused layer2 projection (R0 body, contiguous node range) ----
__global__ __launch_bounds__(256) void agg_proj_kernel(const bf16* __restrict__ P1,
                                                       const int* __restrict__ row_start,
                                                       const int* __restrict__ csr_src,
                                                       const float* __restrict__ dinv,
                                                       const float* __restrict__ b1,
                                                       const float* __restrict__ W2,
                                                       bf16* __restrict__ P2, int N) {
    __shared__ float Wl[4096];
    for (int i = threadIdx.x; i < 4096; i += 256) Wl[i] = W2[i];
    __syncthreads();
    int lane = threadIdx.x & 63;
    int r = lane >> 3, c = lane & 7;
    float bb[8];
#pragma unroll
    for (int k = 0; k < 8; ++k) bb[k] = b1[c * 8 + k];
    int wid = (blockIdx.x * 256 + threadIdx.x) >> 6;
    int nwaves = (gridDim.x * 256) >> 6;
    int cpn = (N + nwaves - 1) / nwaves;         // contiguous nodes per wave
    int node0 = wid * cpn;
    int node1 = node0 + cpn; if (node1 > N) node1 = N;
    for (int node = node0; node < node1; ++node) {
        float acc[8];
        gather_sum8(acc, P1, csr_src, row_start[node], row_start[node + 1], r, c);
        // self-loop chunk (added once per lane, after reduction)
        uint4 vs = *(const uint4*)(P1 + (size_t)node * 64 + c * 8);
        acc_bf8(acc, vs, 1.f);
        float dv = dinv[node];
        float h[8];
#pragma unroll
        for (int k = 0; k < 8; ++k) h[k] = fmaxf(acc[k] * dv + bb[k], 0.f);
        // fused projection: P2[node][lane] = (h1 @ W2)[lane] * dinv
        float acc2 = 0.f;
#pragma unroll
        for (int c2 = 0; c2 < 8; ++c2) {
#pragma unroll
            for (int j = 0; j < 8; ++j) {
                acc2 += __shfl(h[j], c2) * Wl[(c2 * 8 + j) * 64 + lane];
            }
        }
        P2[(size_t)node * 64 + lane] = __float2bfloat16(acc2 * dv);
    }
}

// ---- layer2 aggregate + fused mean-pool accumulation (R0 body, contiguous range) ----
__global__ __launch_bounds__(256) void agg_pool_kernel(const bf16* __restrict__ P2,
                                                       const int* __restrict__ row_start,
                                                       const int* __restrict__ csr_src,
                                                       const float* __restrict__ dinv,
                                                       const float* __restrict__ b2,
                                                       const int* __restrict__ batch,
                                                       float* __restrict__ out_h,
                                                       float* __restrict__ accum, int N) {
    int lane = threadIdx.x & 63;
    int r = lane >> 3, c = lane & 7;
    float bb[8];
#pragma unroll
    for (int k = 0; k < 8; ++k) bb[k] = b2[c * 8 + k];
    // transpose source lane: holds c' = lane>>3, i.e. features (lane>>3)*8+k
    int src = ((lane & 7) << 3) | (lane >> 3);
    int wid = (blockIdx.x * 256 + threadIdx.x) >> 6;
    int nwaves = (gridDim.x * 256) >> 6;
    int cpn = (N + nwaves - 1) / nwaves;
    int node0 = wid * cpn;
    int node1 = node0 + cpn; if (node1 > N) node1 = N;
    for (int node = node0; node < node1; ++node) {
        float acc[8];
        gather_sum8(acc, P2, csr_src, row_start[node], row_start[node + 1], r, c);
        uint4 vs = *(const uint4*)(P2 + (size_t)node * 64 + c * 8);
        acc_bf8(acc, vs, 1.f);
        float dv = dinv[node];
        float h[8];
#pragma unroll
        for (int k = 0; k < 8; ++k) h[k] = acc[k] * dv + bb[k];
        // in-register transpose: lane l ends up holding feature l
        float val = 0.f;
#pragma unroll
        for (int k = 0; k < 8; ++k) {
            float t = __shfl(h[k], src);
            val = ((lane & 7) == k) ? t : val;
        }
        // coalesced wave-wide store (256 B contiguous) + ONE wave-wide atomic
        out_h[(size_t)node * 64 + lane] = val;
        int g = batch[node];
        g = max(0, min(g, NGRAPH - 1));
        atomicAdd(&accum[g * 64 + lane], val);
    }
}

// ---------------- finalize pool (divide by count) + classifier head ----------------
__device__ __forceinline__ int lower_bound_dev(const int* a, int n, int key) {
    int lo = 0, hi = n;
    while (lo < hi) {
        int mid = (lo + hi) >> 1;
        if (a[mid] < key) lo = mid + 1; else hi = mid;
    }
    return lo;
}

__global__ __launch_bounds__(64) void final_kernel(const float* __restrict__ accum,
                                                   const int* __restrict__ batch,
                                                   const float* __restrict__ Wc1,
                                                   const float* __restrict__ bc1,
                                                   const float* __restrict__ Wc2,
                                                   const float* __restrict__ bc2,
                                                   float* __restrict__ out_reps,
                                                   float* __restrict__ out_logits, int N) {
    __shared__ float rep[64];
    __shared__ float t[64];
    int g = blockIdx.x;
    int f = threadIdx.x;
    int lo = lower_bound_dev(batch, N, g);
    int hi = lower_bound_dev(batch, N, g + 1);
    float cnt = (float)(hi - lo);
    float r = accum[g * 64 + f] / fmaxf(cnt, 1.f);
    out_reps[g * 64 + f] = r;
    rep[f] = r;
    __syncthreads();
    float acc = bc1[f];
#pragma unroll
    for (int k = 0; k < 64; ++k) acc += rep[k] * Wc1[k * 64 + f];
    t[f] = fmaxf(acc, 0.f);
    __syncthreads();
    if (f < 16) {
        float a2 = bc2[f];
#pragma unroll
        for (int k = 0; k < 64; ++k) a2 += t[k] * Wc2[k * 16 + f];
        out_logits[g * 16 + f] = a2;
    }
}

extern "C" void kernel_launch(void* const* d_in, const int* in_sizes, int n_in,
                              void* d_out, int out_size, void* d_ws, size_t ws_size,
                              hipStream_t stream) {
    const float* x    = (const float*)d_in[0];
    const int*   ei   = (const int*)d_in[1];
    const int*   batch= (const int*)d_in[2];
    const float* W1   = (const float*)d_in[3];
    const float* b1   = (const float*)d_in[4];
    const float* W2   = (const float*)d_in[5];
    const float* b2   = (const float*)d_in[6];
    const float* Wc1  = (const float*)d_in[7];
    const float* bc1  = (const float*)d_in[8];
    const float* Wc2  = (const float*)d_in[9];
    const float* bc2  = (const float*)d_in[10];

    const int N = in_sizes[2];          // 50000
    const int E = in_sizes[1] / 2;      // 800000

    // ---- workspace layout (~7.3 MB) ----
    char* ws = (char*)d_ws;
    size_t off = 0;
    auto alloc = [&](size_t bytes) { void* p = ws + off; off += (bytes + 255) & ~(size_t)255; return p; };
    int*   deg       = (int*)  alloc((size_t)N * 4);
    int*   cursor    = (int*)  alloc((size_t)N * 4);
    float* accum     = (float*)alloc((size_t)NGRAPH * 64 * 4);
    size_t zero_bytes = off;                       // deg + cursor + accum start at 0
    float* dinv      = (float*)alloc((size_t)N * 4);
    int*   row_start = (int*)  alloc((size_t)(N + 1) * 4);
    int*   bsum      = (int*)  alloc(1024);
    int*   boff      = (int*)  alloc(1024);
    int*   csr_src   = (int*)  alloc((size_t)E * 4);
    bf16*  P1        = (bf16*) alloc((size_t)N * 64 * 2);
    bf16*  P2        = (bf16*) alloc((size_t)N * 64 * 2);
    (void)ws_size; (void)n_in; (void)out_size;

    float* out_h      = (float*)d_out;                      // [N,64]
    float* out_reps   = out_h + (size_t)N * 64;             // [128,64]
    float* out_logits = out_reps + (size_t)NGRAPH * 64;     // [128,16]

    int nbE = (E + 255) / 256;
    int nbN = (N + 255) / 256;
    const int GS = 2048;                 // grid-stride blocks (8192 waves)

    hipMemsetAsync(d_ws, 0, zero_bytes, stream);
    deg_kernel<<<nbE, 256, 0, stream>>>(ei, deg, E, N);
    scan1_kernel<<<nbN, 256, 0, stream>>>(deg, bsum, N);
    scan2_kernel<<<1, 256, 0, stream>>>(bsum, boff, nbN);
    scan3_kernel<<<nbN, 256, 0, stream>>>(deg, boff, row_start, dinv, N);

    // fill and proj are independent after scan3 — run them concurrently
    fillproj_kernel<<<nbE + GS, 256, 0, stream>>>(ei, row_start, cursor, csr_src,
                                                  x, W1, dinv, P1, E, N, nbE);

    agg_proj_kernel<<<GS, 256, 0, stream>>>(P1, row_start, csr_src, dinv, b1, W2, P2, N);
    agg_pool_kernel<<<GS, 256, 0, stream>>>(P2, row_start, csr_src, dinv, b2, batch,
                                            out_h, accum, N);
    final_kernel<<<NGRAPH, 64, 0, stream>>>(accum, batch, Wc1, bc1, Wc2, bc2,
                                            out_reps, out_logits, N);
}

// Round 8
// 254.798 us; speedup vs baseline: 1.3487x; 1.1658x over previous
//
#include <hip/hip_runtime.h>
#include <hip/hip_bf16.h>

typedef __hip_bfloat16 bf16;

#define NGRAPH 128
#define MAXNB 256      // max coarse buckets (N <= 65536); nb = ceil(N/256)
#define BCAP 8192      // LDS staging capacity per bucket (avg bucket = 4096 edges)

// ---------------- B1: coarse bucket histogram (dst >> 8) ----------------
__global__ __launch_bounds__(256) void bucket_count_kernel(const int* __restrict__ ei,
                                                           int* __restrict__ bucket_cnt,
                                                           int E, int N, int nb) {
    __shared__ int hist[MAXNB];
    for (int i = threadIdx.x; i < nb; i += 256) hist[i] = 0;
    __syncthreads();
    int stride = gridDim.x * 256;
    for (int e = blockIdx.x * 256 + threadIdx.x; e < E; e += stride) {
        int d = ei[E + e];
        d = max(0, min(d, N - 1));
        atomicAdd(&hist[d >> 8], 1);
    }
    __syncthreads();
    for (int i = threadIdx.x; i < nb; i += 256) {
        int c = hist[i];
        if (c) atomicAdd(&bucket_cnt[i], c);
    }
}

// ---------------- B2: scan bucket counts -> bucket_off, init bucket_cur ----------------
__global__ __launch_bounds__(256) void bucket_scan_kernel(const int* __restrict__ bucket_cnt,
                                                          int* __restrict__ bucket_off,
                                                          int* __restrict__ bucket_cur, int nb) {
    __shared__ int tmp[256];
    int tid = threadIdx.x;
    int v = (tid < nb) ? bucket_cnt[tid] : 0;
    tmp[tid] = v;
    __syncthreads();
    for (int off = 1; off < 256; off <<= 1) {
        int t = (tid >= off) ? tmp[tid - off] : 0;
        __syncthreads();
        tmp[tid] += t;
        __syncthreads();
    }
    int excl = tmp[tid] - v;
    if (tid < nb) { bucket_off[tid] = excl; bucket_cur[tid] = excl; }
    if (tid == nb - 1) bucket_off[nb] = excl + v;   // = E
}

// ---------------- B3: scatter edges into bucket-contiguous pair buffer ----------------
// Each WG: LDS count of its contiguous edge chunk, ONE global reservation per
// touched bucket (<=nb atomics/WG), then LDS-cursor append. Writes to each
// bucket region are clustered (~chunk/nb entries = one cacheline per WG).
__global__ __launch_bounds__(256) void bucket_scatter_kernel(const int* __restrict__ ei,
                                                             int* __restrict__ bucket_cur,
                                                             int2* __restrict__ pairbuf,
                                                             int E, int N, int nb) {
    __shared__ int hist[MAXNB];
    int nwg = gridDim.x;
    int chunk = (E + nwg - 1) / nwg;
    int e0 = blockIdx.x * chunk;
    int e1 = e0 + chunk; if (e1 > E) e1 = E;
    if (e0 >= e1) return;
    for (int i = threadIdx.x; i < nb; i += 256) hist[i] = 0;
    __syncthreads();
    // pass 1: count chunk edges per bucket
    for (int e = e0 + threadIdx.x; e < e1; e += 256) {
        int d = ei[E + e];
        d = max(0, min(d, N - 1));
        atomicAdd(&hist[d >> 8], 1);
    }
    __syncthreads();
    // reserve global ranges: hist[i] becomes this WG's running cursor
    for (int i = threadIdx.x; i < nb; i += 256) {
        int c = hist[i];
        hist[i] = c ? atomicAdd(&bucket_cur[i], c) : 0;
    }
    __syncthreads();
    // pass 2: append (src,dst) pairs
    for (int e = e0 + threadIdx.x; e < e1; e += 256) {
        int s = ei[e];     s = max(0, min(s, N - 1));
        int d = ei[E + e]; d = max(0, min(d, N - 1));
        int pos = atomicAdd(&hist[d >> 8], 1);
        pairbuf[pos] = make_int2(s, d);
    }
}

// ---------------- B4: per-bucket degree + dinv + row_start + counting sort ----------------
__global__ __launch_bounds__(256) void bucket_build_kernel(const int2* __restrict__ pairbuf,
                                                           const int* __restrict__ bucket_off,
                                                           int* __restrict__ row_start,
                                                           float* __restrict__ dinv,
                                                           int* __restrict__ csr_src,
                                                           int E, int N, int nb) {
    __shared__ int deg_l[256];
    __shared__ int cur_l[256];
    __shared__ int stage[BCAP];
    int b = blockIdx.x;              // grid = nb
    int node0 = b << 8;
    int nn = N - node0; if (nn > 256) nn = 256;
    int p0 = bucket_off[b], p1 = bucket_off[b + 1];
    int ne = p1 - p0;
    int tid = threadIdx.x;
    deg_l[tid] = 0;
    __syncthreads();
    for (int i = p0 + tid; i < p1; i += 256) {
        int d = pairbuf[i].y;        // in [node0, node0+nn)
        atomicAdd(&deg_l[d - node0], 1);
    }
    __syncthreads();
    int v = deg_l[tid];
    for (int off = 1; off < 256; off <<= 1) {
        int t = (tid >= off) ? deg_l[tid - off] : 0;
        __syncthreads();
        deg_l[tid] += t;
        __syncthreads();
    }
    int excl = deg_l[tid] - v;
    if (tid < nn) {
        row_start[node0 + tid] = p0 + excl;
        dinv[node0 + tid] = rsqrtf((float)(v + 1));   // +1 self loop
    }
    if (b == nb - 1 && tid == nn - 1) row_start[N] = p0 + excl + v;   // = E
    cur_l[tid] = excl;
    __syncthreads();
    if (ne <= BCAP) {
        for (int i = p0 + tid; i < p1; i += 256) {
            int2 pr = pairbuf[i];
            int pos = atomicAdd(&cur_l[pr.y - node0], 1);
            stage[pos] = pr.x;
        }
        __syncthreads();
        for (int i = tid; i < ne; i += 256) csr_src[p0 + i] = stage[i];
    } else {
        // statistically-never fallback (bucket > BCAP edges): direct scatter
        for (int i = p0 + tid; i < p1; i += 256) {
            int2 pr = pairbuf[i];
            int pos = atomicAdd(&cur_l[pr.y - node0], 1);
            csr_src[p0 + pos] = pr.x;
        }
    }
}

// ---------------- P1 = (x @ W1) * dinv  (wave-per-node, grid-stride; R0 body) ----------------
__global__ __launch_bounds__(256) void proj_kernel(const float* __restrict__ A,
                                                   const float* __restrict__ W,
                                                   const float* __restrict__ dinv,
                                                   bf16* __restrict__ P, int N) {
    __shared__ float Wl[4096];
    for (int i = threadIdx.x; i < 4096; i += 256) Wl[i] = W[i];
    __syncthreads();
    int lane = threadIdx.x & 63;
    int wid = (blockIdx.x * 256 + threadIdx.x) >> 6;
    int nwaves = (gridDim.x * 256) >> 6;
    for (int node = wid; node < N; node += nwaves) {
        float a = A[(size_t)node * 64 + lane];
        float acc = 0.f;
#pragma unroll
        for (int k = 0; k < 64; ++k) acc += __shfl(a, k) * Wl[k * 64 + lane];
        P[(size_t)node * 64 + lane] = __float2bfloat16(acc * dinv[node]);
    }
}

// ---- unpack uint4 (8 bf16) and accumulate with weight w ----
__device__ __forceinline__ void acc_bf8(float* acc, uint4 v, float w) {
    unsigned int u[4] = {v.x, v.y, v.z, v.w};
#pragma unroll
    for (int m = 0; m < 4; ++m) {
        float lo = __uint_as_float(u[m] << 16);
        float hi = __uint_as_float(u[m] & 0xffff0000u);
        acc[2 * m]     += w * lo;
        acc[2 * m + 1] += w * hi;
    }
}

// ---- wide gather: 8 rows per load instruction, unroll x2 (16 rows in flight).
//      EXACT R0 body (proven 64-VGPR dual-stream codegen). ----
__device__ __forceinline__ void gather_sum8(float* acc,
                                            const bf16* __restrict__ P,
                                            const int* __restrict__ csr_src,
                                            int beg, int end, int r, int c) {
#pragma unroll
    for (int k = 0; k < 8; ++k) acc[k] = 0.f;
    for (int i = beg; i < end; i += 16) {
        int r0 = i + r, r1 = i + 8 + r;
        int ok0 = (r0 < end), ok1 = (r1 < end);
        int s0 = ok0 ? csr_src[r0] : 0;
        int s1 = ok1 ? csr_src[r1] : 0;
        float w0 = ok0 ? 1.f : 0.f;
        float w1 = ok1 ? 1.f : 0.f;
        uint4 v0 = *(const uint4*)(P + (size_t)s0 * 64 + c * 8);
        uint4 v1 = *(const uint4*)(P + (size_t)s1 * 64 + c * 8);
        acc_bf8(acc, v0, w0);
        acc_bf8(acc, v1, w1);
    }
    // butterfly-reduce across the 8 r-groups (lane bits 3..5)
#pragma unroll
    for (int mask = 8; mask <= 32; mask <<= 1) {
#pragma unroll
        for (int k = 0; k < 8; ++k) acc[k] += __shfl_xor(acc[k], mask);
    }
}

// ---- layer1 aggregate + fused layer2 projection (R0 body, contiguous node range) ----
__global__ __launch_bounds__(256) void agg_proj_kernel(const bf16* __restrict__ P1,
                                                       const int* __restrict__ row_start,
                                                       const int* __restrict__ csr_src,
                                                       const float* __restrict__ dinv,
                                                       const float* __restrict__ b1,
                                                       const float* __restrict__ W2,
                                                       bf16* __restrict__ P2, int N) {
    __shared__ float Wl[4096];
    for (int i = threadIdx.x; i < 4096; i += 256) Wl[i] = W2[i];
    __syncthreads();
    int lane = threadIdx.x & 63;
    int r = lane >> 3, c = lane & 7;
    float bb[8];
#pragma unroll
    for (int k = 0; k < 8; ++k) bb[k] = b1[c * 8 + k];
    int wid = (blockIdx.x * 256 + threadIdx.x) >> 6;
    int nwaves = (gridDim.x * 256) >> 6;
    int cpn = (N + nwaves - 1) / nwaves;         // contiguous nodes per wave
    int node0 = wid * cpn;
    int node1 = node0 + cpn; if (node1 > N) node1 = N;
    for (int node = node0; node < node1; ++node) {
        float acc[8];
        gather_sum8(acc, P1, csr_src, row_start[node], row_start[node + 1], r, c);
        // self-loop chunk (added once per lane, after reduction)
        uint4 vs = *(const uint4*)(P1 + (size_t)node * 64 + c * 8);
        acc_bf8(acc, vs, 1.f);
        float dv = dinv[node];
        float h[8];
#pragma unroll
        for (int k = 0; k < 8; ++k) h[k] = fmaxf(acc[k] * dv + bb[k], 0.f);
        // fused projection: P2[node][lane] = (h1 @ W2)[lane] * dinv
        float acc2 = 0.f;
#pragma unroll
        for (int c2 = 0; c2 < 8; ++c2) {
#pragma unroll
            for (int j = 0; j < 8; ++j) {
                acc2 += __shfl(h[j], c2) * Wl[(c2 * 8 + j) * 64 + lane];
            }
        }
        P2[(size_t)node * 64 + lane] = __float2bfloat16(acc2 * dv);
    }
}

// ---- layer2 aggregate + fused mean-pool accumulation (R0 body, contiguous range) ----
__global__ __launch_bounds__(256) void agg_pool_kernel(const bf16* __restrict__ P2,
                                                       const int* __restrict__ row_start,
                                                       const int* __restrict__ csr_src,
                                                       const float* __restrict__ dinv,
                                                       const float* __restrict__ b2,
                                                       const int* __restrict__ batch,
                                                       float* __restrict__ out_h,
                                                       float* __restrict__ accum, int N) {
    int lane = threadIdx.x & 63;
    int r = lane >> 3, c = lane & 7;
    float bb[8];
#pragma unroll
    for (int k = 0; k < 8; ++k) bb[k] = b2[c * 8 + k];
    // transpose source lane: holds c' = lane>>3, i.e. features (lane>>3)*8+k
    int src = ((lane & 7) << 3) | (lane >> 3);
    int wid = (blockIdx.x * 256 + threadIdx.x) >> 6;
    int nwaves = (gridDim.x * 256) >> 6;
    int cpn = (N + nwaves - 1) / nwaves;
    int node0 = wid * cpn;
    int node1 = node0 + cpn; if (node1 > N) node1 = N;
    for (int node = node0; node < node1; ++node) {
        float acc[8];
        gather_sum8(acc, P2, csr_src, row_start[node], row_start[node + 1], r, c);
        uint4 vs = *(const uint4*)(P2 + (size_t)node * 64 + c * 8);
        acc_bf8(acc, vs, 1.f);
        float dv = dinv[node];
        float h[8];
#pragma unroll
        for (int k = 0; k < 8; ++k) h[k] = acc[k] * dv + bb[k];
        // in-register transpose: lane l ends up holding feature l
        float val = 0.f;
#pragma unroll
        for (int k = 0; k < 8; ++k) {
            float t = __shfl(h[k], src);
            val = ((lane & 7) == k) ? t : val;
        }
        // coalesced wave-wide store (256 B contiguous) + ONE wave-wide atomic
        out_h[(size_t)node * 64 + lane] = val;
        int g = batch[node];
        g = max(0, min(g, NGRAPH - 1));
        atomicAdd(&accum[g * 64 + lane], val);
    }
}

// ---------------- finalize pool (divide by count) + classifier head ----------------
__device__ __forceinline__ int lower_bound_dev(const int* a, int n, int key) {
    int lo = 0, hi = n;
    while (lo < hi) {
        int mid = (lo + hi) >> 1;
        if (a[mid] < key) lo = mid + 1; else hi = mid;
    }
    return lo;
}

__global__ __launch_bounds__(64) void final_kernel(const float* __restrict__ accum,
                                                   const int* __restrict__ batch,
                                                   const float* __restrict__ Wc1,
                                                   const float* __restrict__ bc1,
                                                   const float* __restrict__ Wc2,
                                                   const float* __restrict__ bc2,
                                                   float* __restrict__ out_reps,
                                                   float* __restrict__ out_logits, int N) {
    __shared__ float rep[64];
    __shared__ float t[64];
    int g = blockIdx.x;
    int f = threadIdx.x;
    int lo = lower_bound_dev(batch, N, g);
    int hi = lower_bound_dev(batch, N, g + 1);
    float cnt = (float)(hi - lo);
    float r = accum[g * 64 + f] / fmaxf(cnt, 1.f);
    out_reps[g * 64 + f] = r;
    rep[f] = r;
    __syncthreads();
    float acc = bc1[f];
#pragma unroll
    for (int k = 0; k < 64; ++k) acc += rep[k] * Wc1[k * 64 + f];
    t[f] = fmaxf(acc, 0.f);
    __syncthreads();
    if (f < 16) {
        float a2 = bc2[f];
#pragma unroll
        for (int k = 0; k < 64; ++k) a2 += t[k] * Wc2[k * 16 + f];
        out_logits[g * 16 + f] = a2;
    }
}

extern "C" void kernel_launch(void* const* d_in, const int* in_sizes, int n_in,
                              void* d_out, int out_size, void* d_ws, size_t ws_size,
                              hipStream_t stream) {
    const float* x    = (const float*)d_in[0];
    const int*   ei   = (const int*)d_in[1];
    const int*   batch= (const int*)d_in[2];
    const float* W1   = (const float*)d_in[3];
    const float* b1   = (const float*)d_in[4];
    const float* W2   = (const float*)d_in[5];
    const float* b2   = (const float*)d_in[6];
    const float* Wc1  = (const float*)d_in[7];
    const float* bc1  = (const float*)d_in[8];
    const float* Wc2  = (const float*)d_in[9];
    const float* bc2  = (const float*)d_in[10];

    const int N = in_sizes[2];          // 50000
    const int E = in_sizes[1] / 2;      // 800000
    const int nb = (N + 255) >> 8;      // coarse buckets (196 for N=50000)

    // ---- workspace layout (~16.6 MB; pairbuf aliases P2 region) ----
    char* ws = (char*)d_ws;
    size_t off = 0;
    auto alloc = [&](size_t bytes) { void* p = ws + off; off += (bytes + 255) & ~(size_t)255; return p; };
    float* accum      = (float*)alloc((size_t)NGRAPH * 64 * 4);
    int*   bucket_cnt = (int*)  alloc((size_t)MAXNB * 4);
    size_t zero_bytes = off;                       // accum + bucket_cnt start at 0
    int*   bucket_off = (int*)  alloc((size_t)(MAXNB + 1) * 4);
    int*   bucket_cur = (int*)  alloc((size_t)MAXNB * 4);
    float* dinv       = (float*)alloc((size_t)N * 4);
    int*   row_start  = (int*)  alloc((size_t)(N + 1) * 4);
    int*   csr_src    = (int*)  alloc((size_t)E * 4);
    bf16*  P1         = (bf16*) alloc((size_t)N * 64 * 2);
    size_t p2_bytes   = (size_t)N * 64 * 2;
    size_t pair_bytes = (size_t)E * 8;
    void*  p2_region  = alloc(p2_bytes > pair_bytes ? p2_bytes : pair_bytes);
    bf16*  P2         = (bf16*)p2_region;          // live: agg_proj -> agg_pool
    int2*  pairbuf    = (int2*)p2_region;          // live: B3 -> B4 (disjoint lifetime)
    (void)ws_size; (void)n_in; (void)out_size;

    float* out_h      = (float*)d_out;                      // [N,64]
    float* out_reps   = out_h + (size_t)N * 64;             // [128,64]
    float* out_logits = out_reps + (size_t)NGRAPH * 64;     // [128,16]

    const int GS = 2048;                 // grid-stride blocks (8192 waves)

    hipMemsetAsync(d_ws, 0, zero_bytes, stream);
    bucket_count_kernel<<<256, 256, 0, stream>>>(ei, bucket_cnt, E, N, nb);
    bucket_scan_kernel<<<1, 256, 0, stream>>>(bucket_cnt, bucket_off, bucket_cur, nb);
    bucket_scatter_kernel<<<256, 256, 0, stream>>>(ei, bucket_cur, pairbuf, E, N, nb);
    bucket_build_kernel<<<nb, 256, 0, stream>>>(pairbuf, bucket_off, row_start, dinv,
                                                csr_src, E, N, nb);

    proj_kernel<<<GS, 256, 0, stream>>>(x, W1, dinv, P1, N);
    agg_proj_kernel<<<GS, 256, 0, stream>>>(P1, row_start, csr_src, dinv, b1, W2, P2, N);
    agg_pool_kernel<<<GS, 256, 0, stream>>>(P2, row_start, csr_src, dinv, b2, batch,
                                            out_h, accum, N);
    final_kernel<<<NGRAPH, 64, 0, stream>>>(accum, batch, Wc1, bc1, Wc2, bc2,
                                            out_reps, out_logits, N);
}